// Round 14
// baseline (81.014 us; speedup 1.0000x reference)
//
#include <hip/hip_runtime.h>

// CenterLossForward:
//   loss        = LAMBDA/BATCH * sum_b ||batch_b - centers[y_b]||^2
//   new_centers = centers; new_centers[y_b] += ALPHA*(batch_b - centers[y_b])  (dups accumulate)
// d_out layout: [loss (1 float)] [new_centers (NUM_CLASSES*EMBED floats)]
//
// R14: R13 fused row pass + (1) loss via per-wave atomicAdd (out[0] zeroed in
// init kernel; reduce dispatch dropped), (2) 2 rows per wave-iteration with
// all 4 row loads issued before the dependent shfl-realign chains (2x MLP).

constexpr int   NUM_CLASSES = 100000;
constexpr int   EMBED       = 512;
constexpr int   BATCH       = 4096;
constexpr float LAMBDA      = 0.01f;
constexpr float ALPHA       = 0.1f;

constexpr long  NFLOAT = (long)NUM_CLASSES * EMBED;   // 51,200,000

typedef float f4 __attribute__((ext_vector_type(4)));

__global__ void init_head_kernel(int* __restrict__ head, float* __restrict__ out) {
    int c = blockIdx.x * blockDim.x + threadIdx.x;
    if (c < NUM_CLASSES) head[c] = -1;
    if (c == 0) out[0] = 0.f;
}

__global__ void link_kernel(const int* __restrict__ y, int* __restrict__ head,
                            int* __restrict__ nxt) {
    int s = blockIdx.x * blockDim.x + threadIdx.x;
    if (s < BATCH) nxt[s] = atomicExch(&head[y[s]], s);
}

// Per row r (owned by one wave): row floats src[512r..512r+511] as 2 f4/lane.
// Output floats [1+512r .. 512r+512]:
//   f4 group j=i*64+lane: dst4[128r+1+j] = {v_j.w, v_{j+1}.xyz}
//   lane0 scalars dst[1..3 +512r], lane63 scalar dst[512r+512].
__device__ __forceinline__ void process_row(
        int r, int lane,
        const f4* __restrict__ src4, const f4* __restrict__ batch4,
        f4* __restrict__ dst4, float* __restrict__ dst,
        const int* __restrict__ head, const int* __restrict__ nxt,
        float& lacc, f4 c0, f4 c1) {
    const long base = 128L * r;

    int s = head[r];                           // wave-uniform
    if (s >= 0) {
        f4 a0 = {0.f, 0.f, 0.f, 0.f}, a1 = a0;
        do {
            const long bb = 128L * s;
            f4 b0 = batch4[bb + lane];
            f4 b1 = batch4[bb + 64 + lane];
            f4 d0 = b0 - c0;
            f4 d1 = b1 - c1;
            a0 += d0;
            a1 += d1;
            lacc += d0.x * d0.x + d0.y * d0.y + d0.z * d0.z + d0.w * d0.w
                  + d1.x * d1.x + d1.y * d1.y + d1.z * d1.z + d1.w * d1.w;
            s = nxt[s];
        } while (s >= 0);
        c0 += ALPHA * a0;
        c1 += ALPHA * a1;
    }

    // realign: group j needs v_{j+1}.xyz (next lane; c0 lane63 -> lane0's c1)
    float c1x0 = __shfl(c1.x, 0, 64);
    float c1y0 = __shfl(c1.y, 0, 64);
    float c1z0 = __shfl(c1.z, 0, 64);
    float n0x = __shfl_down(c0.x, 1, 64);
    float n0y = __shfl_down(c0.y, 1, 64);
    float n0z = __shfl_down(c0.z, 1, 64);
    float n1x = __shfl_down(c1.x, 1, 64);
    float n1y = __shfl_down(c1.y, 1, 64);
    float n1z = __shfl_down(c1.z, 1, 64);
    if (lane == 63) { n0x = c1x0; n0y = c1y0; n0z = c1z0; }

    f4 o0 = {c0.w, n0x, n0y, n0z};
    __builtin_nontemporal_store(o0, &dst4[base + 1 + lane]);
    if (lane < 63) {
        f4 o1 = {c1.w, n1x, n1y, n1z};
        __builtin_nontemporal_store(o1, &dst4[base + 65 + lane]);
    }
    if (lane == 0) {
        dst[1 + 512L * r] = c0.x;
        dst[2 + 512L * r] = c0.y;
        dst[3 + 512L * r] = c0.z;
    }
    if (lane == 63) {
        dst[512L * r + 512] = c1.w;
    }
}

__global__ void __launch_bounds__(256) fused_rows_kernel(
        const f4* __restrict__ src4,
        const f4* __restrict__ batch4,
        f4* __restrict__ dst4,
        const float* __restrict__ src,
        float* __restrict__ dst,
        const int* __restrict__ head,
        const int* __restrict__ nxt,
        float* __restrict__ out0) {
    const int lane = threadIdx.x & 63;
    const int wid  = threadIdx.x >> 6;
    const int gw   = blockIdx.x * 4 + wid;
    const int nw   = gridDim.x * 4;

    float lacc = 0.f;
    // 2 rows per iteration: loads for both rows issued before either shfl chain
    for (int r0 = 2 * gw; r0 < NUM_CLASSES; r0 += 2 * nw) {
        const int  r1 = r0 + 1;                    // NUM_CLASSES even -> r1 valid
        const long b0 = 128L * r0;
        const long b1 = 128L * r1;
        f4 x0 = src4[b0 + lane];
        f4 x1 = src4[b0 + 64 + lane];
        f4 y0 = src4[b1 + lane];
        f4 y1 = src4[b1 + 64 + lane];

        process_row(r0, lane, src4, batch4, dst4, dst, head, nxt, lacc, x0, x1);
        process_row(r1, lane, src4, batch4, dst4, dst, head, nxt, lacc, y0, y1);
    }

    #pragma unroll
    for (int off = 32; off > 0; off >>= 1) lacc += __shfl_xor(lacc, off, 64);
    if (lane == 0 && lacc != 0.f) atomicAdd(out0, lacc * (LAMBDA / (float)BATCH));
}

// ---- fallback (ws too small): blit + per-sample atomics ----
__global__ void center_update_fallback(const int* __restrict__ y,
                                       const float4* __restrict__ batch,
                                       const float4* __restrict__ centers,
                                       float* __restrict__ out) {
    const int b = blockIdx.x, t = threadIdx.x;
    const int cls = y[b];
    const float4 xb = batch[(size_t)b * (EMBED / 4) + t];
    const float4 c  = centers[(size_t)cls * (EMBED / 4) + t];
    const float dx = xb.x - c.x, dy = xb.y - c.y, dz = xb.z - c.z, dw = xb.w - c.w;
    float* orow = out + 1 + (size_t)cls * EMBED + (size_t)t * 4;
    atomicAdd(orow + 0, ALPHA * dx);
    atomicAdd(orow + 1, ALPHA * dy);
    atomicAdd(orow + 2, ALPHA * dz);
    atomicAdd(orow + 3, ALPHA * dw);
    float s = dx * dx + dy * dy + dz * dz + dw * dw;
    #pragma unroll
    for (int off = 32; off > 0; off >>= 1) s += __shfl_down(s, off, 64);
    __shared__ float wsum[2];
    const int lane = t & 63, wid = t >> 6;
    if (lane == 0) wsum[wid] = s;
    __syncthreads();
    if (t == 0) atomicAdd(out, (wsum[0] + wsum[1]) * (LAMBDA / (float)BATCH));
}

extern "C" void kernel_launch(void* const* d_in, const int* in_sizes, int n_in,
                              void* d_out, int out_size, void* d_ws, size_t ws_size,
                              hipStream_t stream) {
    const int*   y       = (const int*)d_in[0];
    const float* batch   = (const float*)d_in[1];
    const float* centers = (const float*)d_in[2];
    float*       out     = (float*)d_out;

    const size_t head_bytes = (size_t)NUM_CLASSES * sizeof(int);
    const size_t next_bytes = (size_t)BATCH * sizeof(int);

    if (ws_size >= head_bytes + next_bytes) {
        int* head = (int*)d_ws;
        int* nxt  = (int*)((char*)d_ws + head_bytes);

        init_head_kernel<<<(NUM_CLASSES + 1023) / 1024, 1024, 0, stream>>>(head, out);
        link_kernel<<<(BATCH + 255) / 256, 256, 0, stream>>>(y, head, nxt);
        fused_rows_kernel<<<2048, 256, 0, stream>>>(
            (const f4*)centers, (const f4*)batch, (f4*)out,
            centers, out, head, nxt, out);
    } else {
        (void)hipMemsetAsync(out, 0, sizeof(float), stream);
        (void)hipMemcpyAsync(out + 1, centers, NFLOAT * sizeof(float),
                             hipMemcpyDeviceToDevice, stream);
        center_update_fallback<<<BATCH, EMBED / 4, 0, stream>>>(
            y, (const float4*)batch, (const float4*)centers, out);
    }
}

// Round 15
// 80.644 us; speedup vs baseline: 1.0046x; 1.0046x over previous
//
#include <hip/hip_runtime.h>

// CenterLossForward:
//   loss        = LAMBDA/BATCH * sum_b ||batch_b - centers[y_b]||^2
//   new_centers = centers; new_centers[y_b] += ALPHA*(batch_b - centers[y_b])  (dups accumulate)
// d_out layout: [loss (1 float)] [new_centers (NUM_CLASSES*EMBED floats)]
//
// R15 = R13's fused row pass verbatim (best measured: 79.6us; 1 row per
// wave-iteration) + loss via per-wave atomicAdd with out[0] zeroed in init
// (drops the reduce dispatch). R14's 2-row unroll reverted (VGPR 24->32 and
// worse store locality; 81.0us).

constexpr int   NUM_CLASSES = 100000;
constexpr int   EMBED       = 512;
constexpr int   BATCH       = 4096;
constexpr float LAMBDA      = 0.01f;
constexpr float ALPHA       = 0.1f;

constexpr long  NFLOAT = (long)NUM_CLASSES * EMBED;   // 51,200,000

typedef float f4 __attribute__((ext_vector_type(4)));

__global__ void init_head_kernel(int* __restrict__ head, float* __restrict__ out) {
    int c = blockIdx.x * blockDim.x + threadIdx.x;
    if (c < NUM_CLASSES) head[c] = -1;
    if (c == 0) out[0] = 0.f;
}

__global__ void link_kernel(const int* __restrict__ y, int* __restrict__ head,
                            int* __restrict__ nxt) {
    int s = blockIdx.x * blockDim.x + threadIdx.x;
    if (s < BATCH) nxt[s] = atomicExch(&head[y[s]], s);
}

// One wave per row r. Row floats: src[512r .. 512r+511] as 2 f4/lane.
// Output dst floats: [1+512r .. 512r+512]:
//   f4 group j=i*64+lane: dst4[128r+1+j] = {v_j.w, v_{j+1}.xyz}
//   lane0 scalars dst[1..3 +512r], lane63 scalar dst[512r+512].
__global__ void __launch_bounds__(256) fused_rows_kernel(
        const f4* __restrict__ src4,
        const f4* __restrict__ batch4,
        f4* __restrict__ dst4,
        const float* __restrict__ src,
        float* __restrict__ dst,
        const int* __restrict__ head,
        const int* __restrict__ nxt,
        float* __restrict__ out0) {
    const int lane = threadIdx.x & 63;
    const int wid  = threadIdx.x >> 6;
    const int gw   = blockIdx.x * 4 + wid;
    const int nw   = gridDim.x * 4;

    float lacc = 0.f;
    for (int r = gw; r < NUM_CLASSES; r += nw) {
        const long base = 128L * r;
        f4 c0 = src4[base + lane];
        f4 c1 = src4[base + 64 + lane];

        int s = head[r];                       // wave-uniform
        if (s >= 0) {
            f4 a0 = {0.f, 0.f, 0.f, 0.f}, a1 = a0;
            do {
                const long bb = 128L * s;
                f4 b0 = batch4[bb + lane];
                f4 b1 = batch4[bb + 64 + lane];
                f4 d0 = b0 - c0;
                f4 d1 = b1 - c1;
                a0 += d0;
                a1 += d1;
                lacc += d0.x * d0.x + d0.y * d0.y + d0.z * d0.z + d0.w * d0.w
                      + d1.x * d1.x + d1.y * d1.y + d1.z * d1.z + d1.w * d1.w;
                s = nxt[s];
            } while (s >= 0);
            c0 += ALPHA * a0;
            c1 += ALPHA * a1;
        }

        // realign: group j needs v_{j+1}.xyz (next lane; c0 lane63 -> lane0's c1)
        float c1x0 = __shfl(c1.x, 0, 64);
        float c1y0 = __shfl(c1.y, 0, 64);
        float c1z0 = __shfl(c1.z, 0, 64);
        float n0x = __shfl_down(c0.x, 1, 64);
        float n0y = __shfl_down(c0.y, 1, 64);
        float n0z = __shfl_down(c0.z, 1, 64);
        float n1x = __shfl_down(c1.x, 1, 64);
        float n1y = __shfl_down(c1.y, 1, 64);
        float n1z = __shfl_down(c1.z, 1, 64);
        if (lane == 63) { n0x = c1x0; n0y = c1y0; n0z = c1z0; }

        f4 o0 = {c0.w, n0x, n0y, n0z};
        __builtin_nontemporal_store(o0, &dst4[base + 1 + lane]);
        if (lane < 63) {
            f4 o1 = {c1.w, n1x, n1y, n1z};
            __builtin_nontemporal_store(o1, &dst4[base + 65 + lane]);
        }
        if (lane == 0) {
            dst[1 + 512L * r] = c0.x;
            dst[2 + 512L * r] = c0.y;
            dst[3 + 512L * r] = c0.z;
        }
        if (lane == 63) {
            dst[512L * r + 512] = c1.w;
        }
    }

    #pragma unroll
    for (int off = 32; off > 0; off >>= 1) lacc += __shfl_xor(lacc, off, 64);
    if (lane == 0 && lacc != 0.f) atomicAdd(out0, lacc * (LAMBDA / (float)BATCH));
}

// ---- fallback (ws too small): blit + per-sample atomics ----
__global__ void center_update_fallback(const int* __restrict__ y,
                                       const float4* __restrict__ batch,
                                       const float4* __restrict__ centers,
                                       float* __restrict__ out) {
    const int b = blockIdx.x, t = threadIdx.x;
    const int cls = y[b];
    const float4 xb = batch[(size_t)b * (EMBED / 4) + t];
    const float4 c  = centers[(size_t)cls * (EMBED / 4) + t];
    const float dx = xb.x - c.x, dy = xb.y - c.y, dz = xb.z - c.z, dw = xb.w - c.w;
    float* orow = out + 1 + (size_t)cls * EMBED + (size_t)t * 4;
    atomicAdd(orow + 0, ALPHA * dx);
    atomicAdd(orow + 1, ALPHA * dy);
    atomicAdd(orow + 2, ALPHA * dz);
    atomicAdd(orow + 3, ALPHA * dw);
    float s = dx * dx + dy * dy + dz * dz + dw * dw;
    #pragma unroll
    for (int off = 32; off > 0; off >>= 1) s += __shfl_down(s, off, 64);
    __shared__ float wsum[2];
    const int lane = t & 63, wid = t >> 6;
    if (lane == 0) wsum[wid] = s;
    __syncthreads();
    if (t == 0) atomicAdd(out, (wsum[0] + wsum[1]) * (LAMBDA / (float)BATCH));
}

extern "C" void kernel_launch(void* const* d_in, const int* in_sizes, int n_in,
                              void* d_out, int out_size, void* d_ws, size_t ws_size,
                              hipStream_t stream) {
    const int*   y       = (const int*)d_in[0];
    const float* batch   = (const float*)d_in[1];
    const float* centers = (const float*)d_in[2];
    float*       out     = (float*)d_out;

    const size_t head_bytes = (size_t)NUM_CLASSES * sizeof(int);
    const size_t next_bytes = (size_t)BATCH * sizeof(int);

    if (ws_size >= head_bytes + next_bytes) {
        int* head = (int*)d_ws;
        int* nxt  = (int*)((char*)d_ws + head_bytes);

        init_head_kernel<<<(NUM_CLASSES + 1023) / 1024, 1024, 0, stream>>>(head, out);
        link_kernel<<<(BATCH + 255) / 256, 256, 0, stream>>>(y, head, nxt);
        fused_rows_kernel<<<2048, 256, 0, stream>>>(
            (const f4*)centers, (const f4*)batch, (f4*)out,
            centers, out, head, nxt, out);
    } else {
        (void)hipMemsetAsync(out, 0, sizeof(float), stream);
        (void)hipMemcpyAsync(out + 1, centers, NFLOAT * sizeof(float),
                             hipMemcpyDeviceToDevice, stream);
        center_update_fallback<<<BATCH, EMBED / 4, 0, stream>>>(
            y, (const float4*)batch, (const float4*)centers, out);
    }
}